// Round 10
// baseline (143.199 us; speedup 1.0000x reference)
//
#include <hip/hip_runtime.h>

#define IMG_H 512
#define IMG_W 512
#define NIMG  32
#define RPW   2                      // output rows per wave
#define NWAVE 4                      // waves per block
#define ROWS_PER_BLOCK (RPW * NWAVE) // 8
#define STRIPS (IMG_H / ROWS_PER_BLOCK) // 64 strips per image
#define NBLK (NIMG * STRIPS)         // 2048 blocks

__device__ __forceinline__ float sh_up(float v, int lane) {
    float t = __shfl_up(v, 1, 64);
    return lane == 0 ? 0.f : t;
}
__device__ __forceinline__ float sh_dn(float v, int lane) {
    float t = __shfl_down(v, 1, 64);
    return lane == 63 ? 0.f : t;
}

// load one row's 8 columns for this lane (zeros outside the image)
__device__ __forceinline__ void rowvals(const float* __restrict__ p, int y, float* x) {
    if ((unsigned)y < (unsigned)IMG_H) {
        const float4* q = (const float4*)(p + (size_t)y * IMG_W);
        float4 a = q[0], b = q[1];
        x[0] = a.x; x[1] = a.y; x[2] = a.z; x[3] = a.w;
        x[4] = b.x; x[5] = b.y; x[6] = b.z; x[7] = b.w;
    } else {
        #pragma unroll
        for (int k = 0; k < 8; ++k) x[k] = 0.f;
    }
}

__device__ __forceinline__ void accrow(const float* x1, const float* x2,
        float* s1, float* s2, float* s11, float* s22, float* s12) {
    #pragma unroll
    for (int k = 0; k < 8; ++k) {
        s1[k] += x1[k]; s2[k] += x2[k];
        s11[k] = fmaf(x1[k], x1[k], s11[k]);
        s22[k] = fmaf(x2[k], x2[k], s22[k]);
        s12[k] = fmaf(x1[k], x2[k], s12[k]);
    }
}
__device__ __forceinline__ void subrow(const float* x1, const float* x2,
        float* s1, float* s2, float* s11, float* s22, float* s12) {
    #pragma unroll
    for (int k = 0; k < 8; ++k) {
        s1[k] -= x1[k]; s2[k] -= x2[k];
        s11[k] = fmaf(-x1[k], x1[k], s11[k]);
        s22[k] = fmaf(-x2[k], x2[k], s22[k]);
        s12[k] = fmaf(-x1[k], x2[k], s12[k]);
    }
}

// horizontal 7-box-sum: v[0..7] = this lane's 8 column values (vertical sums),
// halo via lane+-1 shuffles, sliding-window in registers.
__device__ __forceinline__ void hbox(const float* v, float* h, int lane) {
    float l5 = sh_up(v[5], lane), l6 = sh_up(v[6], lane), l7 = sh_up(v[7], lane);
    float r0 = sh_dn(v[0], lane), r1 = sh_dn(v[1], lane), r2 = sh_dn(v[2], lane);
    h[0] = ((l5 + l6) + (l7 + v[0])) + ((v[1] + v[2]) + v[3]);
    h[1] = h[0] - l5   + v[4];
    h[2] = h[1] - l6   + v[5];
    h[3] = h[2] - l7   + v[6];
    h[4] = h[3] - v[0] + v[7];
    h[5] = h[4] - v[1] + r0;
    h[6] = h[5] - v[2] + r1;
    h[7] = h[6] - v[3] + r2;
}

// one output row: horizontal sums + SSIM formula, returns partial sum
__device__ __forceinline__ float rowssim(const float* s1, const float* s2,
        const float* s11, const float* s22, const float* s12, int lane) {
    constexpr float C1f = 1e-4f;   // (0.01)^2
    constexpr float C2f = 9e-4f;   // (0.03)^2
    float h1[8], h2[8], h11[8], h22[8], h12[8];
    hbox(s1,  h1,  lane);
    hbox(s2,  h2,  lane);
    hbox(s11, h11, lane);
    hbox(s22, h22, lane);
    hbox(s12, h12, lane);
    float acc = 0.f;
    #pragma unroll
    for (int k = 0; k < 8; ++k) {
        const float mu1 = h1[k], mu2 = h2[k];
        const float mu11 = mu1 * mu1, mu22 = mu2 * mu2, mu12 = mu1 * mu2;
        const float sg1  = h11[k] - mu11;
        const float sg2  = h22[k] - mu22;
        const float sg12 = h12[k] - mu12;
        const float num = (2.f * mu12 + C1f) * (2.f * sg12 + C2f);
        const float den = (mu11 + mu22 + C1f) * (sg1 + sg2 + C2f);
        float r = __builtin_amdgcn_rcpf(den);
        r = r * (2.0f - den * r);          // den > 0 always; 1 Newton step
        acc = fmaf(num, r, acc);
    }
    return acc;
}

// (256,6): VGPR cap 512/6=85 — matches the 84 this kernel naturally uses at
// (256,2), while requesting 6 waves/SIMD residency instead of 2. Single-
// variable A/B vs round 7 (which measured occupancy ~2 waves/SIMD, the
// apparent waves-per-EU bound).
extern "C" __global__ void __launch_bounds__(256, 6)
ssim_main(const float* __restrict__ img1, const float* __restrict__ img2,
          float* __restrict__ partials)
{
    const int tid  = threadIdx.x;
    const int lane = tid & 63;
    const int wv   = tid >> 6;

    // XCD-aware swizzle: 2048 blocks, 8 XCDs -> each XCD gets 4 whole images
    const int bid   = blockIdx.x;
    const int xcd   = bid & 7;
    const int idx   = bid >> 3;           // 0..255
    const int img   = xcd * (NIMG / 8) + (idx >> 6);
    const int strip = idx & 63;
    const int wy0   = strip * ROWS_PER_BLOCK + wv * RPW;

    const size_t base = (size_t)img * (IMG_H * IMG_W) + (size_t)(lane << 3);
    const float* p1 = img1 + base;
    const float* p2 = img2 + base;

    // Window rows q0..q7 = wy0-3 .. wy0+4.
    //   output row wy0   = box over q0..q6
    //   output row wy0+1 = box over q1..q7
    // ALL 8 row-pair loads issued upfront into distinct statically-indexed
    // buffers -> one global_load burst, single latency exposure per wave.
    float b0a[8], b0b[8], b1a[8], b1b[8], b2a[8], b2b[8], b3a[8], b3b[8];
    float b4a[8], b4b[8], b5a[8], b5b[8], b6a[8], b6b[8], b7a[8], b7b[8];

    rowvals(p1, wy0 - 3, b0a); rowvals(p2, wy0 - 3, b0b);
    rowvals(p1, wy0 - 2, b1a); rowvals(p2, wy0 - 2, b1b);
    rowvals(p1, wy0 - 1, b2a); rowvals(p2, wy0 - 1, b2b);
    rowvals(p1, wy0 + 0, b3a); rowvals(p2, wy0 + 0, b3b);
    rowvals(p1, wy0 + 1, b4a); rowvals(p2, wy0 + 1, b4b);
    rowvals(p1, wy0 + 2, b5a); rowvals(p2, wy0 + 2, b5b);
    rowvals(p1, wy0 + 3, b6a); rowvals(p2, wy0 + 3, b6b);
    rowvals(p1, wy0 + 4, b7a); rowvals(p2, wy0 + 4, b7b);

    float s1[8], s2[8], s11[8], s22[8], s12[8];
    #pragma unroll
    for (int k = 0; k < 8; ++k) { s1[k] = s2[k] = s11[k] = s22[k] = s12[k] = 0.f; }

    accrow(b0a, b0b, s1, s2, s11, s22, s12);   // +q0
    accrow(b1a, b1b, s1, s2, s11, s22, s12);   // +q1
    accrow(b2a, b2b, s1, s2, s11, s22, s12);   // +q2
    accrow(b3a, b3b, s1, s2, s11, s22, s12);   // +q3
    accrow(b4a, b4b, s1, s2, s11, s22, s12);   // +q4
    accrow(b5a, b5b, s1, s2, s11, s22, s12);   // +q5
    accrow(b6a, b6b, s1, s2, s11, s22, s12);   // +q6  (window q0..q6)

    float acc = rowssim(s1, s2, s11, s22, s12, lane);     // row wy0

    subrow(b0a, b0b, s1, s2, s11, s22, s12);   // -q0
    accrow(b7a, b7b, s1, s2, s11, s22, s12);   // +q7  (window q1..q7)

    acc += rowssim(s1, s2, s11, s22, s12, lane);          // row wy0+1

    // block reduction: wave shuffle-reduce then LDS across 4 waves
    #pragma unroll
    for (int off = 32; off; off >>= 1) acc += __shfl_down(acc, off, 64);

    __shared__ float red[NWAVE];
    if (lane == 0) red[wv] = acc;
    __syncthreads();
    if (tid == 0) {
        partials[bid] = (red[0] + red[1]) + (red[2] + red[3]);
    }
}

extern "C" __global__ void __launch_bounds__(64)
ssim_final(const float* __restrict__ partials, float* __restrict__ out)
{
    const int lane = threadIdx.x;
    double s = 0.0;
    #pragma unroll
    for (int i = 0; i < NBLK / 64; ++i) s += (double)partials[lane + (i << 6)];
    #pragma unroll
    for (int off = 32; off; off >>= 1) s += __shfl_down(s, off, 64);
    if (lane == 0) {
        out[0] = (float)(1.0 - s / ((double)NIMG * IMG_H * IMG_W));
    }
}

extern "C" void kernel_launch(void* const* d_in, const int* in_sizes, int n_in,
                              void* d_out, int out_size, void* d_ws, size_t ws_size,
                              hipStream_t stream) {
    const float* img1 = (const float*)d_in[0];
    const float* img2 = (const float*)d_in[1];
    float* partials = (float*)d_ws;   // NBLK floats

    hipLaunchKernelGGL(ssim_main, dim3(NBLK), dim3(256), 0, stream,
                       img1, img2, partials);
    hipLaunchKernelGGL(ssim_final, dim3(1), dim3(64), 0, stream,
                       partials, (float*)d_out);
}

// Round 11
// 41.881 us; speedup vs baseline: 3.4192x; 3.4192x over previous
//
#include <hip/hip_runtime.h>

#define IMG_H 512
#define IMG_W 512
#define NIMG  32
#define RPW   2                      // output rows per wave
#define NWAVE 4                      // waves per block
#define ROWS_PER_BLOCK (RPW * NWAVE) // 8
#define STRIPS (IMG_H / ROWS_PER_BLOCK) // 64 strips per image
#define NBLK (NIMG * STRIPS)         // 2048 blocks

__device__ __forceinline__ float sh_up(float v, int lane) {
    float t = __shfl_up(v, 1, 64);
    return lane == 0 ? 0.f : t;
}
__device__ __forceinline__ float sh_dn(float v, int lane) {
    float t = __shfl_down(v, 1, 64);
    return lane == 63 ? 0.f : t;
}

// load one row's 8 columns for this lane (zeros outside the image)
__device__ __forceinline__ void rowvals(const float* __restrict__ p, int y, float* x) {
    if ((unsigned)y < (unsigned)IMG_H) {
        const float4* q = (const float4*)(p + (size_t)y * IMG_W);
        float4 a = q[0], b = q[1];
        x[0] = a.x; x[1] = a.y; x[2] = a.z; x[3] = a.w;
        x[4] = b.x; x[5] = b.y; x[6] = b.z; x[7] = b.w;
    } else {
        #pragma unroll
        for (int k = 0; k < 8; ++k) x[k] = 0.f;
    }
}

__device__ __forceinline__ void accrow(const float* x1, const float* x2,
        float* s1, float* s2, float* s11, float* s22, float* s12) {
    #pragma unroll
    for (int k = 0; k < 8; ++k) {
        s1[k] += x1[k]; s2[k] += x2[k];
        s11[k] = fmaf(x1[k], x1[k], s11[k]);
        s22[k] = fmaf(x2[k], x2[k], s22[k]);
        s12[k] = fmaf(x1[k], x2[k], s12[k]);
    }
}
__device__ __forceinline__ void subrow(const float* x1, const float* x2,
        float* s1, float* s2, float* s11, float* s22, float* s12) {
    #pragma unroll
    for (int k = 0; k < 8; ++k) {
        s1[k] -= x1[k]; s2[k] -= x2[k];
        s11[k] = fmaf(-x1[k], x1[k], s11[k]);
        s22[k] = fmaf(-x2[k], x2[k], s22[k]);
        s12[k] = fmaf(-x1[k], x2[k], s12[k]);
    }
}

// horizontal 7-box-sum: v[0..7] = this lane's 8 column values (vertical sums),
// halo via lane+-1 shuffles, sliding-window in registers.
__device__ __forceinline__ void hbox(const float* v, float* h, int lane) {
    float l5 = sh_up(v[5], lane), l6 = sh_up(v[6], lane), l7 = sh_up(v[7], lane);
    float r0 = sh_dn(v[0], lane), r1 = sh_dn(v[1], lane), r2 = sh_dn(v[2], lane);
    h[0] = ((l5 + l6) + (l7 + v[0])) + ((v[1] + v[2]) + v[3]);
    h[1] = h[0] - l5   + v[4];
    h[2] = h[1] - l6   + v[5];
    h[3] = h[2] - l7   + v[6];
    h[4] = h[3] - v[0] + v[7];
    h[5] = h[4] - v[1] + r0;
    h[6] = h[5] - v[2] + r1;
    h[7] = h[6] - v[3] + r2;
}

// one output row: horizontal sums + SSIM formula, returns partial sum
__device__ __forceinline__ float rowssim(const float* s1, const float* s2,
        const float* s11, const float* s22, const float* s12, int lane) {
    constexpr float C1f = 1e-4f;   // (0.01)^2
    constexpr float C2f = 9e-4f;   // (0.03)^2
    float h1[8], h2[8], h11[8], h22[8], h12[8];
    hbox(s1,  h1,  lane);
    hbox(s2,  h2,  lane);
    hbox(s11, h11, lane);
    hbox(s22, h22, lane);
    hbox(s12, h12, lane);
    float acc = 0.f;
    #pragma unroll
    for (int k = 0; k < 8; ++k) {
        const float mu1 = h1[k], mu2 = h2[k];
        const float mu11 = mu1 * mu1, mu22 = mu2 * mu2, mu12 = mu1 * mu2;
        const float sg1  = h11[k] - mu11;
        const float sg2  = h22[k] - mu22;
        const float sg12 = h12[k] - mu12;
        const float num = (2.f * mu12 + C1f) * (2.f * sg12 + C2f);
        const float den = (mu11 + mu22 + C1f) * (sg1 + sg2 + C2f);
        float r = __builtin_amdgcn_rcpf(den);
        r = r * (2.0f - den * r);          // den > 0 always; 1 Newton step
        acc = fmaf(num, r, acc);
    }
    return acc;
}

// NO __launch_bounds__: clang's second arg pins amdgpu-waves-per-eu, which
// measured as a residency CAP (occupancy tracked the arg across rounds
// 2/3/7/10, even when VGPRs allowed 3x more). Default attributes let the
// HW host 2048/~88 = ~23 waves/CU (~6/SIMD) at this kernel's natural ~84
// VGPR allocation.
extern "C" __global__ void
ssim_main(const float* __restrict__ img1, const float* __restrict__ img2,
          float* __restrict__ partials)
{
    const int tid  = threadIdx.x;
    const int lane = tid & 63;
    const int wv   = tid >> 6;

    // XCD-aware swizzle: 2048 blocks, 8 XCDs -> each XCD gets 4 whole images
    const int bid   = blockIdx.x;
    const int xcd   = bid & 7;
    const int idx   = bid >> 3;           // 0..255
    const int img   = xcd * (NIMG / 8) + (idx >> 6);
    const int strip = idx & 63;
    const int wy0   = strip * ROWS_PER_BLOCK + wv * RPW;

    const size_t base = (size_t)img * (IMG_H * IMG_W) + (size_t)(lane << 3);
    const float* p1 = img1 + base;
    const float* p2 = img2 + base;

    // Window rows q0..q7 = wy0-3 .. wy0+4.
    //   output row wy0   = box over q0..q6
    //   output row wy0+1 = box over q1..q7
    // ALL 8 row-pair loads issued upfront into distinct statically-indexed
    // buffers -> one global_load burst, single latency exposure per wave.
    float b0a[8], b0b[8], b1a[8], b1b[8], b2a[8], b2b[8], b3a[8], b3b[8];
    float b4a[8], b4b[8], b5a[8], b5b[8], b6a[8], b6b[8], b7a[8], b7b[8];

    rowvals(p1, wy0 - 3, b0a); rowvals(p2, wy0 - 3, b0b);
    rowvals(p1, wy0 - 2, b1a); rowvals(p2, wy0 - 2, b1b);
    rowvals(p1, wy0 - 1, b2a); rowvals(p2, wy0 - 1, b2b);
    rowvals(p1, wy0 + 0, b3a); rowvals(p2, wy0 + 0, b3b);
    rowvals(p1, wy0 + 1, b4a); rowvals(p2, wy0 + 1, b4b);
    rowvals(p1, wy0 + 2, b5a); rowvals(p2, wy0 + 2, b5b);
    rowvals(p1, wy0 + 3, b6a); rowvals(p2, wy0 + 3, b6b);
    rowvals(p1, wy0 + 4, b7a); rowvals(p2, wy0 + 4, b7b);

    float s1[8], s2[8], s11[8], s22[8], s12[8];
    #pragma unroll
    for (int k = 0; k < 8; ++k) { s1[k] = s2[k] = s11[k] = s22[k] = s12[k] = 0.f; }

    accrow(b0a, b0b, s1, s2, s11, s22, s12);   // +q0
    accrow(b1a, b1b, s1, s2, s11, s22, s12);   // +q1
    accrow(b2a, b2b, s1, s2, s11, s22, s12);   // +q2
    accrow(b3a, b3b, s1, s2, s11, s22, s12);   // +q3
    accrow(b4a, b4b, s1, s2, s11, s22, s12);   // +q4
    accrow(b5a, b5b, s1, s2, s11, s22, s12);   // +q5
    accrow(b6a, b6b, s1, s2, s11, s22, s12);   // +q6  (window q0..q6)

    float acc = rowssim(s1, s2, s11, s22, s12, lane);     // row wy0

    subrow(b0a, b0b, s1, s2, s11, s22, s12);   // -q0
    accrow(b7a, b7b, s1, s2, s11, s22, s12);   // +q7  (window q1..q7)

    acc += rowssim(s1, s2, s11, s22, s12, lane);          // row wy0+1

    // block reduction: wave shuffle-reduce then LDS across 4 waves
    #pragma unroll
    for (int off = 32; off; off >>= 1) acc += __shfl_down(acc, off, 64);

    __shared__ float red[NWAVE];
    if (lane == 0) red[wv] = acc;
    __syncthreads();
    if (tid == 0) {
        partials[bid] = (red[0] + red[1]) + (red[2] + red[3]);
    }
}

extern "C" __global__ void __launch_bounds__(64)
ssim_final(const float* __restrict__ partials, float* __restrict__ out)
{
    const int lane = threadIdx.x;
    double s = 0.0;
    #pragma unroll
    for (int i = 0; i < NBLK / 64; ++i) s += (double)partials[lane + (i << 6)];
    #pragma unroll
    for (int off = 32; off; off >>= 1) s += __shfl_down(s, off, 64);
    if (lane == 0) {
        out[0] = (float)(1.0 - s / ((double)NIMG * IMG_H * IMG_W));
    }
}

extern "C" void kernel_launch(void* const* d_in, const int* in_sizes, int n_in,
                              void* d_out, int out_size, void* d_ws, size_t ws_size,
                              hipStream_t stream) {
    const float* img1 = (const float*)d_in[0];
    const float* img2 = (const float*)d_in[1];
    float* partials = (float*)d_ws;   // NBLK floats

    hipLaunchKernelGGL(ssim_main, dim3(NBLK), dim3(256), 0, stream,
                       img1, img2, partials);
    hipLaunchKernelGGL(ssim_final, dim3(1), dim3(64), 0, stream,
                       partials, (float*)d_out);
}

// Round 12
// 30.998 us; speedup vs baseline: 4.6197x; 1.3511x over previous
//
#include <hip/hip_runtime.h>

#define IMG_H 512
#define IMG_W 512
#define NIMG  32
#define RPW   2                      // output rows per wave
#define NWAVE 4                      // waves per block
#define ROWS_PER_BLOCK (RPW * NWAVE) // 8
#define STRIPS (IMG_H / ROWS_PER_BLOCK) // 64 strips per image
#define NBLK (NIMG * STRIPS)         // 2048 blocks
#define NROWS 14                     // 8 output rows + 6 halo
#define NITEM (NROWS * 2)            // row-images staged per block

__device__ __forceinline__ float sh_up(float v, int lane) {
    float t = __shfl_up(v, 1, 64);
    return lane == 0 ? 0.f : t;
}
__device__ __forceinline__ float sh_dn(float v, int lane) {
    float t = __shfl_down(v, 1, 64);
    return lane == 63 ? 0.f : t;
}

__device__ __forceinline__ void accrow(const float* x1, const float* x2,
        float* s1, float* s2, float* s11, float* s22, float* s12) {
    #pragma unroll
    for (int k = 0; k < 8; ++k) {
        s1[k] += x1[k]; s2[k] += x2[k];
        s11[k] = fmaf(x1[k], x1[k], s11[k]);
        s22[k] = fmaf(x2[k], x2[k], s22[k]);
        s12[k] = fmaf(x1[k], x2[k], s12[k]);
    }
}
__device__ __forceinline__ void subrow(const float* x1, const float* x2,
        float* s1, float* s2, float* s11, float* s22, float* s12) {
    #pragma unroll
    for (int k = 0; k < 8; ++k) {
        s1[k] -= x1[k]; s2[k] -= x2[k];
        s11[k] = fmaf(-x1[k], x1[k], s11[k]);
        s22[k] = fmaf(-x2[k], x2[k], s22[k]);
        s12[k] = fmaf(-x1[k], x2[k], s12[k]);
    }
}

// horizontal 7-box-sum: halo via lane+-1 shuffles, register sliding window.
__device__ __forceinline__ void hbox(const float* v, float* h, int lane) {
    float l5 = sh_up(v[5], lane), l6 = sh_up(v[6], lane), l7 = sh_up(v[7], lane);
    float r0 = sh_dn(v[0], lane), r1 = sh_dn(v[1], lane), r2 = sh_dn(v[2], lane);
    h[0] = ((l5 + l6) + (l7 + v[0])) + ((v[1] + v[2]) + v[3]);
    h[1] = h[0] - l5   + v[4];
    h[2] = h[1] - l6   + v[5];
    h[3] = h[2] - l7   + v[6];
    h[4] = h[3] - v[0] + v[7];
    h[5] = h[4] - v[1] + r0;
    h[6] = h[5] - v[2] + r1;
    h[7] = h[6] - v[3] + r2;
}

__device__ __forceinline__ float rowssim(const float* s1, const float* s2,
        const float* s11, const float* s22, const float* s12, int lane) {
    constexpr float C1f = 1e-4f;   // (0.01)^2
    constexpr float C2f = 9e-4f;   // (0.03)^2
    float h1[8], h2[8], h11[8], h22[8], h12[8];
    hbox(s1,  h1,  lane);
    hbox(s2,  h2,  lane);
    hbox(s11, h11, lane);
    hbox(s22, h22, lane);
    hbox(s12, h12, lane);
    float acc = 0.f;
    #pragma unroll
    for (int k = 0; k < 8; ++k) {
        const float mu1 = h1[k], mu2 = h2[k];
        const float mu11 = mu1 * mu1, mu22 = mu2 * mu2, mu12 = mu1 * mu2;
        const float sg1  = h11[k] - mu11;
        const float sg2  = h22[k] - mu22;
        const float sg12 = h12[k] - mu12;
        const float num = (2.f * mu12 + C1f) * (2.f * sg12 + C2f);
        const float den = (mu11 + mu22 + C1f) * (sg1 + sg2 + C2f);
        float r = __builtin_amdgcn_rcpf(den);
        r = r * (2.0f - den * r);          // den > 0 always; 1 Newton step
        acc = fmaf(num, r, acc);
    }
    return acc;
}

// (256,2): VGPR cap 128 (measured round 1); LDS (56KB/block) caps occupancy
// at 2 blocks/CU = 2 waves/SIMD anyway, so the wpe pin costs nothing.
extern "C" __global__ void __launch_bounds__(256, 2)
ssim_main(const float* __restrict__ img1, const float* __restrict__ img2,
          float* __restrict__ partials)
{
    // 28 row-images x 512 floats = 57,344 B
    __shared__ float4 lds4[NITEM * 128];

    const int tid  = threadIdx.x;
    const int lane = tid & 63;
    const int wv   = tid >> 6;

    // XCD-aware swizzle: each XCD gets 4 whole images
    const int bid   = blockIdx.x;
    const int xcd   = bid & 7;
    const int idx   = bid >> 3;           // 0..255
    const int img   = xcd * (NIMG / 8) + (idx >> 6);
    const int strip = idx & 63;
    const int wy_blk = strip * ROWS_PER_BLOCK;

    // ---- stage NITEM row-images into LDS, 7 items per wave ----
    // Involution chunk swizzle (m173 pattern): per-lane GLOBAL source chunk
    // c(l) = l ^ (l>>3); LDS dest linear (lane*16 fixed by HW). Chunk j then
    // lives at LDS slot j ^ (j>>3) (involution), and reads use the same map.
    const int c = lane ^ (lane >> 3);
    const size_t ibase = (size_t)img * (IMG_H * IMG_W);

    #pragma unroll
    for (int u = 0; u < 7; ++u) {
        const int t   = wv * 7 + u;       // item: (rel row, image)
        const int rel = t >> 1;
        const int m   = t & 1;
        const int y   = wy_blk - 3 + rel;
        float4* dst = &lds4[t * 128];
        if ((unsigned)y < (unsigned)IMG_H) {   // wave-uniform branch
            const float* src = (m ? img2 : img1) + ibase + (size_t)y * IMG_W;
            const float* g = src + c * 4;      // per-lane swizzled source
            __builtin_amdgcn_global_load_lds(
                (const __attribute__((address_space(1))) void*)g,
                (__attribute__((address_space(3))) void*)dst, 16, 0, 0);
            __builtin_amdgcn_global_load_lds(
                (const __attribute__((address_space(1))) void*)(g + 256),
                (__attribute__((address_space(3))) void*)(dst + 64), 16, 0, 0);
        } else {
            const float4 z = make_float4(0.f, 0.f, 0.f, 0.f);
            dst[lane]      = z;                // zeros are swizzle-invariant
            dst[64 + lane] = z;
        }
    }
    __syncthreads();   // drains vmcnt (global_load_lds) + lgkmcnt

    // ---- read addresses: lane needs chunks 2l, 2l+1 of each row ----
    const int halfsel = lane >> 5;
    const int jj  = (lane & 31) * 2;          // local chunk (even)
    const int pos = jj ^ (jj >> 3);           // slot of chunk jj
    const int f4a = halfsel * 64 + pos;       // chunk jj
    const int f4b = halfsel * 64 + (pos ^ 1); // chunk jj+1 (adjacent slot)

    float s1[8], s2[8], s11[8], s22[8], s12[8];
    #pragma unroll
    for (int k = 0; k < 8; ++k) { s1[k] = s2[k] = s11[k] = s22[k] = s12[k] = 0.f; }

    const int r0 = wv * RPW;   // first rel row this wave needs
    float x1[8], x2[8];

    #pragma unroll
    for (int r = 0; r < 7; ++r) {
        const int t1 = (r0 + r) * 2;
        {
            float4 a = lds4[t1 * 128 + f4a], b = lds4[t1 * 128 + f4b];
            x1[0]=a.x; x1[1]=a.y; x1[2]=a.z; x1[3]=a.w;
            x1[4]=b.x; x1[5]=b.y; x1[6]=b.z; x1[7]=b.w;
        }
        {
            float4 a = lds4[(t1 + 1) * 128 + f4a], b = lds4[(t1 + 1) * 128 + f4b];
            x2[0]=a.x; x2[1]=a.y; x2[2]=a.z; x2[3]=a.w;
            x2[4]=b.x; x2[5]=b.y; x2[6]=b.z; x2[7]=b.w;
        }
        accrow(x1, x2, s1, s2, s11, s22, s12);
    }

    float acc = rowssim(s1, s2, s11, s22, s12, lane);     // row wy_blk + 2wv

    {   // leave row r0 (re-read from LDS), enter row r0+7
        const int t1 = r0 * 2;
        float4 a = lds4[t1 * 128 + f4a], b = lds4[t1 * 128 + f4b];
        x1[0]=a.x; x1[1]=a.y; x1[2]=a.z; x1[3]=a.w;
        x1[4]=b.x; x1[5]=b.y; x1[6]=b.z; x1[7]=b.w;
        float4 a2 = lds4[(t1 + 1) * 128 + f4a], b2 = lds4[(t1 + 1) * 128 + f4b];
        x2[0]=a2.x; x2[1]=a2.y; x2[2]=a2.z; x2[3]=a2.w;
        x2[4]=b2.x; x2[5]=b2.y; x2[6]=b2.z; x2[7]=b2.w;
        subrow(x1, x2, s1, s2, s11, s22, s12);

        const int t2 = (r0 + 7) * 2;
        float4 a3 = lds4[t2 * 128 + f4a], b3 = lds4[t2 * 128 + f4b];
        x1[0]=a3.x; x1[1]=a3.y; x1[2]=a3.z; x1[3]=a3.w;
        x1[4]=b3.x; x1[5]=b3.y; x1[6]=b3.z; x1[7]=b3.w;
        float4 a4 = lds4[(t2 + 1) * 128 + f4a], b4 = lds4[(t2 + 1) * 128 + f4b];
        x2[0]=a4.x; x2[1]=a4.y; x2[2]=a4.z; x2[3]=a4.w;
        x2[4]=b4.x; x2[5]=b4.y; x2[6]=b4.z; x2[7]=b4.w;
        accrow(x1, x2, s1, s2, s11, s22, s12);
    }

    acc += rowssim(s1, s2, s11, s22, s12, lane);          // row wy_blk + 2wv+1

    // block reduction: wave shuffle-reduce then LDS across 4 waves
    #pragma unroll
    for (int off = 32; off; off >>= 1) acc += __shfl_down(acc, off, 64);

    __shared__ float red[NWAVE];
    if (lane == 0) red[wv] = acc;
    __syncthreads();
    if (tid == 0) {
        partials[bid] = (red[0] + red[1]) + (red[2] + red[3]);
    }
}

extern "C" __global__ void __launch_bounds__(64)
ssim_final(const float* __restrict__ partials, float* __restrict__ out)
{
    const int lane = threadIdx.x;
    double s = 0.0;
    #pragma unroll
    for (int i = 0; i < NBLK / 64; ++i) s += (double)partials[lane + (i << 6)];
    #pragma unroll
    for (int off = 32; off; off >>= 1) s += __shfl_down(s, off, 64);
    if (lane == 0) {
        out[0] = (float)(1.0 - s / ((double)NIMG * IMG_H * IMG_W));
    }
}

extern "C" void kernel_launch(void* const* d_in, const int* in_sizes, int n_in,
                              void* d_out, int out_size, void* d_ws, size_t ws_size,
                              hipStream_t stream) {
    const float* img1 = (const float*)d_in[0];
    const float* img2 = (const float*)d_in[1];
    float* partials = (float*)d_ws;   // NBLK floats

    hipLaunchKernelGGL(ssim_main, dim3(NBLK), dim3(256), 0, stream,
                       img1, img2, partials);
    hipLaunchKernelGGL(ssim_final, dim3(1), dim3(64), 0, stream,
                       partials, (float*)d_out);
}

// Round 13
// 24.510 us; speedup vs baseline: 5.8425x; 1.2647x over previous
//
#include <hip/hip_runtime.h>

#define IMG_H 512
#define IMG_W 512
#define NIMG  32
#define RPW   2                      // output rows per wave
#define NWAVE 4                      // waves per block
#define ROWS_PER_BLOCK (RPW * NWAVE) // 8
#define STRIPS (IMG_H / ROWS_PER_BLOCK) // 64 strips per image
#define NBLK (NIMG * STRIPS)         // 2048 blocks

__device__ __forceinline__ float sh_up(float v, int lane) {
    float t = __shfl_up(v, 1, 64);
    return lane == 0 ? 0.f : t;
}
__device__ __forceinline__ float sh_dn(float v, int lane) {
    float t = __shfl_down(v, 1, 64);
    return lane == 63 ? 0.f : t;
}

// load one row's 8 columns for this lane (zeros outside the image)
__device__ __forceinline__ void rowvals(const float* __restrict__ p, int y, float* x) {
    if ((unsigned)y < (unsigned)IMG_H) {
        const float4* q = (const float4*)(p + (size_t)y * IMG_W);
        float4 a = q[0], b = q[1];
        x[0] = a.x; x[1] = a.y; x[2] = a.z; x[3] = a.w;
        x[4] = b.x; x[5] = b.y; x[6] = b.z; x[7] = b.w;
    } else {
        #pragma unroll
        for (int k = 0; k < 8; ++k) x[k] = 0.f;
    }
}

__device__ __forceinline__ void accrow(const float* x1, const float* x2,
        float* s1, float* s2, float* s11, float* s22, float* s12) {
    #pragma unroll
    for (int k = 0; k < 8; ++k) {
        s1[k] += x1[k]; s2[k] += x2[k];
        s11[k] = fmaf(x1[k], x1[k], s11[k]);
        s22[k] = fmaf(x2[k], x2[k], s22[k]);
        s12[k] = fmaf(x1[k], x2[k], s12[k]);
    }
}
__device__ __forceinline__ void subrow(const float* x1, const float* x2,
        float* s1, float* s2, float* s11, float* s22, float* s12) {
    #pragma unroll
    for (int k = 0; k < 8; ++k) {
        s1[k] -= x1[k]; s2[k] -= x2[k];
        s11[k] = fmaf(-x1[k], x1[k], s11[k]);
        s22[k] = fmaf(-x2[k], x2[k], s22[k]);
        s12[k] = fmaf(-x1[k], x2[k], s12[k]);
    }
}

// horizontal 7-box-sum: v[0..7] = this lane's 8 column values (vertical sums),
// halo via lane+-1 shuffles, sliding-window in registers.
__device__ __forceinline__ void hbox(const float* v, float* h, int lane) {
    float l5 = sh_up(v[5], lane), l6 = sh_up(v[6], lane), l7 = sh_up(v[7], lane);
    float r0 = sh_dn(v[0], lane), r1 = sh_dn(v[1], lane), r2 = sh_dn(v[2], lane);
    h[0] = ((l5 + l6) + (l7 + v[0])) + ((v[1] + v[2]) + v[3]);
    h[1] = h[0] - l5   + v[4];
    h[2] = h[1] - l6   + v[5];
    h[3] = h[2] - l7   + v[6];
    h[4] = h[3] - v[0] + v[7];
    h[5] = h[4] - v[1] + r0;
    h[6] = h[5] - v[2] + r1;
    h[7] = h[6] - v[3] + r2;
}

// one output row: horizontal sums + SSIM formula, returns partial sum
__device__ __forceinline__ float rowssim(const float* s1, const float* s2,
        const float* s11, const float* s22, const float* s12, int lane) {
    constexpr float C1f = 1e-4f;   // (0.01)^2
    constexpr float C2f = 9e-4f;   // (0.03)^2
    float h1[8], h2[8], h11[8], h22[8], h12[8];
    hbox(s1,  h1,  lane);
    hbox(s2,  h2,  lane);
    hbox(s11, h11, lane);
    hbox(s22, h22, lane);
    hbox(s12, h12, lane);
    float acc = 0.f;
    #pragma unroll
    for (int k = 0; k < 8; ++k) {
        const float mu1 = h1[k], mu2 = h2[k];
        const float mu11 = mu1 * mu1, mu22 = mu2 * mu2, mu12 = mu1 * mu2;
        const float sg1  = h11[k] - mu11;
        const float sg2  = h22[k] - mu22;
        const float sg12 = h12[k] - mu12;
        const float num = (2.f * mu12 + C1f) * (2.f * sg12 + C2f);
        const float den = (mu11 + mu22 + C1f) * (sg1 + sg2 + C2f);
        float r = __builtin_amdgcn_rcpf(den);
        r = r * (2.0f - den * r);          // den > 0 always; 1 Newton step
        acc = fmaf(num, r, acc);
    }
    return acc;
}

// Decouple register budget from residency throttle:
//  - amdgpu_waves_per_eu(3,8): min=3 keeps the VGPR budget >= this kernel's
//    natural 84 (cap law measured as ~256/min across rounds 1-10), max=8
//    removes the residency pin that held round 7 at 2 waves/SIMD.
//  - HW then hosts 4 waves/SIMD at 84 VGPR (m69: 65-128 VGPR -> 4/SIMD).
extern "C" __global__ void
__attribute__((amdgpu_flat_work_group_size(256, 256), amdgpu_waves_per_eu(3, 8)))
ssim_main(const float* __restrict__ img1, const float* __restrict__ img2,
          float* __restrict__ partials)
{
    const int tid  = threadIdx.x;
    const int lane = tid & 63;
    const int wv   = tid >> 6;

    // XCD-aware swizzle: 2048 blocks, 8 XCDs -> each XCD gets 4 whole images
    const int bid   = blockIdx.x;
    const int xcd   = bid & 7;
    const int idx   = bid >> 3;           // 0..255
    const int img   = xcd * (NIMG / 8) + (idx >> 6);
    const int strip = idx & 63;
    const int wy0   = strip * ROWS_PER_BLOCK + wv * RPW;

    const size_t base = (size_t)img * (IMG_H * IMG_W) + (size_t)(lane << 3);
    const float* p1 = img1 + base;
    const float* p2 = img2 + base;

    // Window rows q0..q7 = wy0-3 .. wy0+4.
    //   output row wy0   = box over q0..q6
    //   output row wy0+1 = box over q1..q7
    // ALL 8 row-pair loads issued upfront into distinct statically-indexed
    // buffers -> one global_load burst, single latency exposure per wave.
    float b0a[8], b0b[8], b1a[8], b1b[8], b2a[8], b2b[8], b3a[8], b3b[8];
    float b4a[8], b4b[8], b5a[8], b5b[8], b6a[8], b6b[8], b7a[8], b7b[8];

    rowvals(p1, wy0 - 3, b0a); rowvals(p2, wy0 - 3, b0b);
    rowvals(p1, wy0 - 2, b1a); rowvals(p2, wy0 - 2, b1b);
    rowvals(p1, wy0 - 1, b2a); rowvals(p2, wy0 - 1, b2b);
    rowvals(p1, wy0 + 0, b3a); rowvals(p2, wy0 + 0, b3b);
    rowvals(p1, wy0 + 1, b4a); rowvals(p2, wy0 + 1, b4b);
    rowvals(p1, wy0 + 2, b5a); rowvals(p2, wy0 + 2, b5b);
    rowvals(p1, wy0 + 3, b6a); rowvals(p2, wy0 + 3, b6b);
    rowvals(p1, wy0 + 4, b7a); rowvals(p2, wy0 + 4, b7b);

    float s1[8], s2[8], s11[8], s22[8], s12[8];
    #pragma unroll
    for (int k = 0; k < 8; ++k) { s1[k] = s2[k] = s11[k] = s22[k] = s12[k] = 0.f; }

    accrow(b0a, b0b, s1, s2, s11, s22, s12);   // +q0
    accrow(b1a, b1b, s1, s2, s11, s22, s12);   // +q1
    accrow(b2a, b2b, s1, s2, s11, s22, s12);   // +q2
    accrow(b3a, b3b, s1, s2, s11, s22, s12);   // +q3
    accrow(b4a, b4b, s1, s2, s11, s22, s12);   // +q4
    accrow(b5a, b5b, s1, s2, s11, s22, s12);   // +q5
    accrow(b6a, b6b, s1, s2, s11, s22, s12);   // +q6  (window q0..q6)

    float acc = rowssim(s1, s2, s11, s22, s12, lane);     // row wy0

    subrow(b0a, b0b, s1, s2, s11, s22, s12);   // -q0
    accrow(b7a, b7b, s1, s2, s11, s22, s12);   // +q7  (window q1..q7)

    acc += rowssim(s1, s2, s11, s22, s12, lane);          // row wy0+1

    // block reduction: wave shuffle-reduce then LDS across 4 waves
    #pragma unroll
    for (int off = 32; off; off >>= 1) acc += __shfl_down(acc, off, 64);

    __shared__ float red[NWAVE];
    if (lane == 0) red[wv] = acc;
    __syncthreads();
    if (tid == 0) {
        partials[bid] = (red[0] + red[1]) + (red[2] + red[3]);
    }
}

extern "C" __global__ void __launch_bounds__(256)
ssim_final(const float* __restrict__ partials, float* __restrict__ out)
{
    // 256 threads: 8 serial loads each (was 32 on one wave), fixed order.
    const int tid  = threadIdx.x;
    const int lane = tid & 63;
    const int wv   = tid >> 6;
    double s = 0.0;
    #pragma unroll
    for (int i = 0; i < NBLK / 256; ++i) s += (double)partials[tid + (i << 8)];
    #pragma unroll
    for (int off = 32; off; off >>= 1) s += __shfl_down(s, off, 64);
    __shared__ double sd[4];
    if (lane == 0) sd[wv] = s;
    __syncthreads();
    if (tid == 0) {
        const double t = (sd[0] + sd[1]) + (sd[2] + sd[3]);
        out[0] = (float)(1.0 - t / ((double)NIMG * IMG_H * IMG_W));
    }
}

extern "C" void kernel_launch(void* const* d_in, const int* in_sizes, int n_in,
                              void* d_out, int out_size, void* d_ws, size_t ws_size,
                              hipStream_t stream) {
    const float* img1 = (const float*)d_in[0];
    const float* img2 = (const float*)d_in[1];
    float* partials = (float*)d_ws;   // NBLK floats

    hipLaunchKernelGGL(ssim_main, dim3(NBLK), dim3(256), 0, stream,
                       img1, img2, partials);
    hipLaunchKernelGGL(ssim_final, dim3(1), dim3(256), 0, stream,
                       partials, (float*)d_out);
}